// Round 4
// baseline (4305.972 us; speedup 1.0000x reference)
//
#include <hip/hip_runtime.h>
#include <cstdint>
#include <cstddef>

#define SEQ   512
#define BATCH 128
#define EMB   1024
#define HID   1024
#define VOCAB 50257
#define GATES 4096  // 4*HID

typedef _Float16 f16x8 __attribute__((ext_vector_type(8)));
typedef float    f32x4 __attribute__((ext_vector_type(4)));
typedef unsigned short u16;
typedef u16 u16x8 __attribute__((ext_vector_type(8)));  // 16-byte transfer unit

__device__ inline u16 f2h(float x) { union { _Float16 h; u16 u; } c; c.h = (_Float16)x; return c.u; }
__device__ inline float h2f(u16 u) { union { u16 u; _Float16 h; } c; c.u = u; return (float)c.h; }

// poison pattern: fp16 NaN 0x7FFF. h = o*tanh(c) in (-1,1) can never encode to it.
#define HPOISON 0x7FFFull

// ---------------- prep kernels ----------------
__global__ void cast_f32_f16_kernel(const float* __restrict__ src, u16* __restrict__ dst, int n4) {
  int i = blockIdx.x * blockDim.x + threadIdx.x;
  int stride = gridDim.x * blockDim.x;
  for (; i < n4; i += stride) {
    float4 v = ((const float4*)src)[i];
    ushort4 o;
    o.x = f2h(v.x); o.y = f2h(v.y); o.z = f2h(v.z); o.w = f2h(v.w);
    ((ushort4*)dst)[i] = o;
  }
}

__global__ void init_kernel(const float* __restrict__ bih, const float* __restrict__ bhh,
                            float* __restrict__ bias, u16* __restrict__ h0, int* __restrict__ sync) {
  int i = blockIdx.x * blockDim.x + threadIdx.x;  // grid 128x256 = 32768
  if (i < GATES) bias[i] = bih[i] + bhh[i];
  ushort4 z; z.x = z.y = z.z = z.w = 0;
  ((ushort4*)h0)[i] = z;                          // slot 0 of hring = h(-1) = 0
  if (i < 8192) sync[i] = 0;                      // WG flags (128x32) + gxcnt[512] at +4096
}

// poison hring slots 1..SEQ (each 8B h-word is written exactly once per dispatch,
// so "data != poison" is a tear-free readiness token; consumers read via LLC-bypass
// atomic loads, so retries never hit a stale L2 line).
__global__ void poison_kernel(u16* __restrict__ hring) {
  const size_t n16 = (size_t)SEQ * BATCH * HID / 8;  // 16B units
  size_t i = (size_t)blockIdx.x * blockDim.x + threadIdx.x;
  const size_t stride = (size_t)gridDim.x * blockDim.x;
  uint4* base = (uint4*)(hring + (size_t)BATCH * HID);
  uint4 pv; pv.x = pv.y = pv.z = pv.w = 0x7FFF7FFFu;
  for (; i < n16; i += stride) base[i] = pv;
}

// ================= FUSED persistent kernel: 256 WGs = 256 CUs =================
// WGs 0..127  : LSTM recurrence. WGs 128..255: embed+W_ih GEMM producer.
// 96 KB dynamic LDS forces 1 WG/CU; grid == CU count guarantees co-residency.
// h sync = DATA-AS-FLAG: consumers spin on poisoned h-words directly (agent-scope
// 8B atomic loads). No per-step flag round trip, no per-step vmcnt(0) store drain.
// WG flags only gate the gx ring (producer back-pressure) + final logsoftmax.
__global__ __launch_bounds__(256, 1) void fused_kernel(
    const u16* __restrict__ embw, const u16* __restrict__ wih,
    const u16* __restrict__ whh, const float* __restrict__ bias,
    const int* __restrict__ X, u16* __restrict__ gx,
    u16* __restrict__ hring, float* __restrict__ hlast,
    float* __restrict__ out, int* __restrict__ flags, int Tc)
{
  extern __shared__ u16 LdsRaw[];
  const int tid = threadIdx.x;
  const int w = tid >> 6, lane = tid & 63;
  int* gxcnt = flags + 4096;   // 512 step-readiness counters (each counts to 32)

  if (blockIdx.x >= 128) {
    // ---------------- producer path: gates_x[t][b][n] = emb[X[t,b]] . W_ih[n]
    u16* Als = LdsRaw;
    u16* Bls = LdsRaw + 4096;
    const int ewg = blockIdx.x - 128;
    const int wm = w & 1, wn = w >> 1;
    const u16* afp = Als + (lane >> 4) * 1024 + (wm * 64 + (lane & 15)) * 8;
    const u16* bfp = Bls + (lane >> 4) * 1024 + (wn * 64 + (lane & 15)) * 8;
    int skq[4], srow[4], shalf[4];
#pragma unroll
    for (int s = 0; s < 4; ++s) {
      const int idx = s * 256 + tid;
      shalf[s] = idx >> 9; skq[s] = (idx >> 7) & 3; srow[s] = idx & 127;
    }
    // tiles t-major: tile = T*32 + colblock; 128 WGs sweep 4 timesteps per pass
    for (int tile = ewg; tile < SEQ * 32; tile += 128) {
      const int T = tile >> 5;
      const int colbase = (tile & 31) << 7;
      // ring back-pressure: slot (T%Tc) free when every consumer passed step T-Tc
      if (T >= Tc) {
        const int need = T - Tc + 1;
        for (;;) {
          int f = __hip_atomic_load(flags + (tid & 127) * 32,
                                    __ATOMIC_RELAXED, __HIP_MEMORY_SCOPE_AGENT);
          if (__syncthreads_and(f >= need)) break;
          __builtin_amdgcn_s_sleep(8);
        }
      }
      size_t sg[4];
#pragma unroll
      for (int s = 0; s < 4; ++s) {
        if (shalf[s] == 0) sg[s] = (size_t)X[(size_t)T * BATCH + srow[s]] * EMB + skq[s] * 8;
        else               sg[s] = (size_t)(colbase + srow[s]) * EMB + skq[s] * 8;
      }
      f32x4 acc[4][4] = {};
      // depth-4 global prefetch queue (statically indexed -> stays in VGPRs)
      u16x8 vq[4][4];
#pragma unroll
      for (int d = 0; d < 4; ++d)
#pragma unroll
        for (int s = 0; s < 4; ++s)
          vq[d][s] = *(const u16x8*)((shalf[s] ? wih : embw) + sg[s] + d * 32);
      for (int kb = 0; kb < 32; kb += 4) {
#pragma unroll
        for (int d = 0; d < 4; ++d) {
#pragma unroll
          for (int s = 0; s < 4; ++s)
            *(u16x8*)((shalf[s] ? Bls : Als) + skq[s] * 1024 + srow[s] * 8) = vq[d][s];
          __syncthreads();
          if (kb + d + 4 < 32) {
#pragma unroll
            for (int s = 0; s < 4; ++s)
              vq[d][s] = *(const u16x8*)((shalf[s] ? wih : embw) + sg[s] + (kb + d + 4) * 32);
          }
          f16x8 af[4], bf[4];
#pragma unroll
          for (int mt = 0; mt < 4; ++mt) af[mt] = *(const f16x8*)(afp + mt * 128);
#pragma unroll
          for (int nt = 0; nt < 4; ++nt) bf[nt] = *(const f16x8*)(bfp + nt * 128);
#pragma unroll
          for (int mt = 0; mt < 4; ++mt)
#pragma unroll
            for (int nt = 0; nt < 4; ++nt)
              acc[mt][nt] = __builtin_amdgcn_mfma_f32_16x16x32_f16(af[mt], bf[nt], acc[mt][nt], 0, 0, 0);
          __syncthreads();
        }
      }
      // store to gx ring slot; agent-scope write-through (consumers on other XCDs)
      const size_t outbase = (size_t)(T % Tc) * ((size_t)GATES * BATCH);
#pragma unroll
      for (int mt = 0; mt < 4; ++mt) {
#pragma unroll
        for (int nt = 0; nt < 4; ++nt) {
          const int n  = colbase + wn * 64 + nt * 16 + (lane & 15);
          const int b0 = wm * 64 + mt * 16 + ((lane >> 4) << 2);
#pragma unroll
          for (int p = 0; p < 4; ++p)
            __hip_atomic_store(gx + outbase + (size_t)(b0 + p) * GATES + n,
                               f2h(acc[mt][nt][p]),
                               __ATOMIC_RELAXED, __HIP_MEMORY_SCOPE_AGENT);
        }
      }
      asm volatile("s_waitcnt vmcnt(0)" ::: "memory");  // all this thread's stores LLC-acked
      __syncthreads();                                   // ... all threads' stores
      if (tid == 0)
        __hip_atomic_fetch_add(gxcnt + T, 1, __ATOMIC_RELAXED, __HIP_MEMORY_SCOPE_AGENT);
    }
    return;
  }

  // ---------------- consumer path: persistent LSTM recurrence ----------------
  f32x4* Red = (f32x4*)LdsRaw;   // [w(4)][g(4)][nt(4)][lane(64)] f32x4 = 64 KB
  const int jloc = lane & 15, lq = lane >> 4;
  const int bh = blockIdx.x & 1;
  const int jw = blockIdx.x >> 1;

  // persistent A-operand: W slice in registers. A[m=jloc][k = w*256 + ks*32 + lq*8 +0..7]
  f16x8 wreg[4][8];
#pragma unroll
  for (int g = 0; g < 4; ++g)
#pragma unroll
    for (int ks = 0; ks < 8; ++ks)
      wreg[g][ks] = *(const f16x8*)(whh + ((size_t)g * HID + jw * 16 + jloc) * HID
                                          + w * 256 + ks * 32 + lq * 8);

  const int b  = bh * 64 + w * 16 + jloc;   // epilogue-owned batch row
  const int j0 = jw * 16 + lq * 4;          // epilogue-owned j base (4 consecutive j)
  f32x4 bs[4];
#pragma unroll
  for (int g = 0; g < 4; ++g) bs[g] = *(const f32x4*)(bias + g * HID + j0);

  f32x4 cc; cc[0] = cc[1] = cc[2] = cc[3] = 0.f;

  // B-load base: jb = w*32 + ks*4 + lq ; b' = bh*64 + nt*16 + jloc
  const u16* hb = hring + (size_t)(w * 32 + lq) * 1024 + (size_t)(bh * 64 + jloc) * 8;
  const int hw_idx = (jw * 2 + (lq >> 1)) * 1024 + b * 8 + (lq & 1) * 4;
  const u16* gbase = gx + (size_t)b * GATES + j0;

  // ---- startup: prefetch gx for t=0 (set A) and t=1 (set B) ----
  unsigned long long vA0, vA1, vA2, vA3, vB0, vB1, vB2, vB3;
  {
    for (;;) {
      int c = __hip_atomic_load(gxcnt + 0, __ATOMIC_RELAXED, __HIP_MEMORY_SCOPE_AGENT);
      if (c >= 32) break;
      __builtin_amdgcn_s_sleep(1);
    }
    vA0 = __hip_atomic_load((const unsigned long long*)(gbase + 0 * 1024), __ATOMIC_RELAXED, __HIP_MEMORY_SCOPE_AGENT);
    vA1 = __hip_atomic_load((const unsigned long long*)(gbase + 1 * 1024), __ATOMIC_RELAXED, __HIP_MEMORY_SCOPE_AGENT);
    vA2 = __hip_atomic_load((const unsigned long long*)(gbase + 2 * 1024), __ATOMIC_RELAXED, __HIP_MEMORY_SCOPE_AGENT);
    vA3 = __hip_atomic_load((const unsigned long long*)(gbase + 3 * 1024), __ATOMIC_RELAXED, __HIP_MEMORY_SCOPE_AGENT);
    for (;;) {
      int c = __hip_atomic_load(gxcnt + 1, __ATOMIC_RELAXED, __HIP_MEMORY_SCOPE_AGENT);
      if (c >= 32) break;
      __builtin_amdgcn_s_sleep(1);
    }
    const u16* g1 = gbase + (size_t)GATES * BATCH;  // slot 1 (Tc >= 8 guaranteed)
    vB0 = __hip_atomic_load((const unsigned long long*)(g1 + 0 * 1024), __ATOMIC_RELAXED, __HIP_MEMORY_SCOPE_AGENT);
    vB1 = __hip_atomic_load((const unsigned long long*)(g1 + 1 * 1024), __ATOMIC_RELAXED, __HIP_MEMORY_SCOPE_AGENT);
    vB2 = __hip_atomic_load((const unsigned long long*)(g1 + 2 * 1024), __ATOMIC_RELAXED, __HIP_MEMORY_SCOPE_AGENT);
    vB3 = __hip_atomic_load((const unsigned long long*)(g1 + 3 * 1024), __ATOMIC_RELAXED, __HIP_MEMORY_SCOPE_AGENT);
  }
  int snext = 2;  // gx ring slot holding step t+2

  union HV { unsigned long long q[2]; f16x8 v; };

  for (int t = 0; t < SEQ; ++t) {
    const u16* ap = hb + (size_t)t * (BATCH * HID);
    // ---- spin directly on h[t] data (poison-validated, LLC-bypass loads) ----
    HV hvv[8][4];
    for (;;) {
      int bad = 0;
#pragma unroll
      for (int ks = 0; ks < 8; ++ks)
#pragma unroll
        for (int nt = 0; nt < 4; ++nt) {
          const unsigned long long* src = (const unsigned long long*)(ap + ks * 4096 + nt * 128);
          hvv[ks][nt].q[0] = __hip_atomic_load(src,     __ATOMIC_RELAXED, __HIP_MEMORY_SCOPE_AGENT);
          hvv[ks][nt].q[1] = __hip_atomic_load(src + 1, __ATOMIC_RELAXED, __HIP_MEMORY_SCOPE_AGENT);
        }
#pragma unroll
      for (int ks = 0; ks < 8; ++ks)
#pragma unroll
        for (int nt = 0; nt < 4; ++nt)
          bad |= (int)((hvv[ks][nt].q[0] & 0xFFFFull) == HPOISON)
               | (int)((hvv[ks][nt].q[1] & 0xFFFFull) == HPOISON);
      if (!__any(bad)) break;
    }
    f32x4 acc[4][4] = {};
#pragma unroll
    for (int ks = 0; ks < 8; ++ks)
#pragma unroll
      for (int g = 0; g < 4; ++g)
#pragma unroll
        for (int nt = 0; nt < 4; ++nt)
          acc[g][nt] = __builtin_amdgcn_mfma_f32_16x16x32_f16(wreg[g][ks], hvv[ks][nt].v, acc[g][nt], 0, 0, 0);
    // early gxcnt probe for t+2: load issues here, value checked after the barrier
    int gxc = 32;
    if (t + 2 < SEQ)
      gxc = __hip_atomic_load(gxcnt + (t + 2), __ATOMIC_RELAXED, __HIP_MEMORY_SCOPE_AGENT);
    // cross-wave K reduction: wave w consumes nt==w outputs
#pragma unroll
    for (int g = 0; g < 4; ++g)
#pragma unroll
      for (int nt = 0; nt < 4; ++nt)
        if (nt != w) Red[((w * 4 + g) * 4 + nt) * 64 + lane] = acc[g][nt];
    __syncthreads();
    f32x4 gate[4];
#pragma unroll
    for (int g = 0; g < 4; ++g) {
      gate[g] = acc[g][w];
#pragma unroll
      for (int wp = 0; wp < 4; ++wp)
        if (wp != w) gate[g] += Red[((wp * 4 + g) * 4 + w) * 64 + lane];
    }
    // parity-select the gx fragment for this step (registers, uniform branch)
    unsigned long long x0, x1, x2, x3;
    if (t & 1) { x0 = vB0; x1 = vB1; x2 = vB2; x3 = vB3; }
    else       { x0 = vA0; x1 = vA1; x2 = vA2; x3 = vA3; }
    u16* hout = hring + (size_t)(t + 1) * (BATCH * HID);
    float hn4[4];
#pragma unroll
    for (int p = 0; p < 4; ++p) {
      float gi = gate[0][p] + h2f((u16)(x0 >> (16 * p))) + bs[0][p];
      float gf = gate[1][p] + h2f((u16)(x1 >> (16 * p))) + bs[1][p];
      float gg = gate[2][p] + h2f((u16)(x2 >> (16 * p))) + bs[2][p];
      float go = gate[3][p] + h2f((u16)(x3 >> (16 * p))) + bs[3][p];
      float ii = 1.f / (1.f + __expf(-gi));
      float ff = 1.f / (1.f + __expf(-gf));
      float e2 = __expf(-2.f * fabsf(gg));
      float tg = copysignf((1.f - e2) / (1.f + e2), gg);
      float oo = 1.f / (1.f + __expf(-go));
      float cn = ff * cc[p] + ii * tg;
      cc[p] = cn;
      float e2c = __expf(-2.f * fabsf(cn));
      float tc = copysignf((1.f - e2c) / (1.f + e2c), cn);
      hn4[p] = oo * tc;
    }
    unsigned long long hp = (unsigned long long)f2h(hn4[0])
                          | ((unsigned long long)f2h(hn4[1]) << 16)
                          | ((unsigned long long)f2h(hn4[2]) << 32)
                          | ((unsigned long long)f2h(hn4[3]) << 48);
    __hip_atomic_store((unsigned long long*)(hout + hw_idx), hp,
                       __ATOMIC_RELAXED, __HIP_MEMORY_SCOPE_AGENT);
    if (t + 1 == SEQ) {  // hlast: agent-scope (read by WGs 0..3 in-dispatch)
      union { float f[2]; unsigned long long u; } pk;
      pk.f[0] = hn4[0]; pk.f[1] = hn4[1];
      __hip_atomic_store((unsigned long long*)(hlast + (size_t)b * HID + j0), pk.u,
                         __ATOMIC_RELAXED, __HIP_MEMORY_SCOPE_AGENT);
      pk.f[0] = hn4[2]; pk.f[1] = hn4[3];
      __hip_atomic_store((unsigned long long*)(hlast + (size_t)b * HID + j0 + 2), pk.u,
                         __ATOMIC_RELAXED, __HIP_MEMORY_SCOPE_AGENT);
    }
    // Red reuse fence + "all waves consumed gx[t]" fence. NO vmcnt drain:
    // h stores flow asynchronously; consumers detect them via the data itself.
    __builtin_amdgcn_s_barrier();
    if (tid == 0 && t + 1 < SEQ)   // flag gates only the gx ring back-pressure
      __hip_atomic_store(flags + blockIdx.x * 32, t + 1,
                         __ATOMIC_RELAXED, __HIP_MEMORY_SCOPE_AGENT);
    if (t + 2 < SEQ) {
      if (gxc < 32) {   // rare after warm-up: producers run ~3x ahead
        const int* cnt = gxcnt + (t + 2);
        for (;;) {
          int c = __hip_atomic_load(cnt, __ATOMIC_RELAXED, __HIP_MEMORY_SCOPE_AGENT);
          if (c >= 32) break;
          __builtin_amdgcn_s_sleep(1);
        }
      }
      const u16* gs = gbase + (size_t)snext * ((size_t)GATES * BATCH);
      if (t & 1) {  // t+2 has same parity: refill the set just consumed
        vB0 = __hip_atomic_load((const unsigned long long*)(gs + 0 * 1024), __ATOMIC_RELAXED, __HIP_MEMORY_SCOPE_AGENT);
        vB1 = __hip_atomic_load((const unsigned long long*)(gs + 1 * 1024), __ATOMIC_RELAXED, __HIP_MEMORY_SCOPE_AGENT);
        vB2 = __hip_atomic_load((const unsigned long long*)(gs + 2 * 1024), __ATOMIC_RELAXED, __HIP_MEMORY_SCOPE_AGENT);
        vB3 = __hip_atomic_load((const unsigned long long*)(gs + 3 * 1024), __ATOMIC_RELAXED, __HIP_MEMORY_SCOPE_AGENT);
      } else {
        vA0 = __hip_atomic_load((const unsigned long long*)(gs + 0 * 1024), __ATOMIC_RELAXED, __HIP_MEMORY_SCOPE_AGENT);
        vA1 = __hip_atomic_load((const unsigned long long*)(gs + 1 * 1024), __ATOMIC_RELAXED, __HIP_MEMORY_SCOPE_AGENT);
        vA2 = __hip_atomic_load((const unsigned long long*)(gs + 2 * 1024), __ATOMIC_RELAXED, __HIP_MEMORY_SCOPE_AGENT);
        vA3 = __hip_atomic_load((const unsigned long long*)(gs + 3 * 1024), __ATOMIC_RELAXED, __HIP_MEMORY_SCOPE_AGENT);
      }
      snext = (snext + 1 == Tc) ? 0 : snext + 1;
    }
  }
  // final: drain hlast + h stores, then publish SEQ (gates logsoftmax WGs)
  asm volatile("s_waitcnt vmcnt(0)" ::: "memory");
  __builtin_amdgcn_s_barrier();
  if (tid == 0)
    __hip_atomic_store(flags + blockIdx.x * 32, SEQ,
                       __ATOMIC_RELAXED, __HIP_MEMORY_SCOPE_AGENT);

  // ---------------- fused log_softmax over BATCH axis (WGs 0..3) ----------------
  if (blockIdx.x < 4) {
    for (;;) {
      int f = __hip_atomic_load(flags + (tid & 127) * 32,
                                __ATOMIC_RELAXED, __HIP_MEMORY_SCOPE_AGENT);
      if (__syncthreads_and(f >= SEQ)) break;
      __builtin_amdgcn_s_sleep(4);
    }
    const int j = blockIdx.x * 256 + tid;
    float m = -1e30f;
    for (int b2 = 0; b2 < BATCH; ++b2) m = fmaxf(m, hlast[(size_t)b2 * HID + j]);
    float s = 0.f;
    for (int b2 = 0; b2 < BATCH; ++b2) s += expf(hlast[(size_t)b2 * HID + j] - m);
    const float lse = m + logf(s);
    for (int b2 = 0; b2 < BATCH; ++b2)
      out[(size_t)b2 * HID + j] = hlast[(size_t)b2 * HID + j] - lse;
  }
}

// ---------------- host ----------------
extern "C" void kernel_launch(void* const* d_in, const int* in_sizes, int n_in,
                              void* d_out, int out_size, void* d_ws, size_t ws_size,
                              hipStream_t stream) {
  const int*   X    = (const int*)d_in[0];
  const float* embd = (const float*)d_in[1];
  const float* wih  = (const float*)d_in[2];
  const float* whh  = (const float*)d_in[3];
  const float* bih  = (const float*)d_in[4];
  const float* bhh  = (const float*)d_in[5];
  float* out = (float*)d_out;

  char* p = (char*)d_ws;
  auto alloc = [&](size_t bytes) { char* r = p; p += (bytes + 255) & ~(size_t)255; return r; };
  u16*   embw    = (u16*)alloc((size_t)VOCAB * EMB * 2);
  u16*   wihh    = (u16*)alloc((size_t)GATES * EMB * 2);
  u16*   whhh    = (u16*)alloc((size_t)GATES * HID * 2);
  float* bias    = (float*)alloc((size_t)GATES * 4);
  u16*   hring   = (u16*)alloc((size_t)(SEQ + 1) * BATCH * HID * 2);
  float* hlast   = (float*)alloc((size_t)BATCH * HID * 4);
  int*   flags   = (int*)alloc(32768);   // 128 WG flags @128B stride + gxcnt[512] @ +16KB
  size_t used = (size_t)(p - (char*)d_ws);
  size_t avail = ws_size > used ? ws_size - used : 0;
  long long Tc = (long long)(avail / ((size_t)GATES * BATCH * 2));
  if (Tc > SEQ) Tc = SEQ;
  if (Tc < 8) return;  // need >= 8 ring slots for the depth-2 gx pipeline
  u16* gx = (u16*)alloc((size_t)Tc * GATES * BATCH * 2);
  int Tci = (int)Tc;

  hipFuncSetAttribute((const void*)fused_kernel, hipFuncAttributeMaxDynamicSharedMemorySize, 98304);

  cast_f32_f16_kernel<<<2048, 256, 0, stream>>>(embd, embw, VOCAB * EMB / 4);
  cast_f32_f16_kernel<<<256, 256, 0, stream>>>(wih, wihh, GATES * EMB / 4);
  cast_f32_f16_kernel<<<256, 256, 0, stream>>>(whh, whhh, GATES * HID / 4);
  init_kernel<<<128, 256, 0, stream>>>(bih, bhh, bias, hring, flags);
  poison_kernel<<<4096, 256, 0, stream>>>(hring);

  // regular launch: 256 WGs x 96KB LDS = 1 WG/CU on 256 CUs -> all co-resident
  fused_kernel<<<dim3(256), dim3(256), 98304, stream>>>(
      embw, wihh, whhh, bias, X, gx, hring, hlast, out, flags, Tci);
}